// Round 9
// baseline (914.946 us; speedup 1.0000x reference)
//
#include <hip/hip_runtime.h>
#include <hip/hip_bf16.h>

#define NB 8192
#define NH 4096
#define NC 1000
#define NE 4
#define NCP 1024   // padded N for gemm2

typedef __attribute__((ext_vector_type(4))) float f32x4;
typedef __attribute__((ext_vector_type(8))) short s16x8;
typedef __attribute__((ext_vector_type(4))) unsigned int u32x4;

__device__ __forceinline__ unsigned cvtpk(float a, float b){
  unsigned r; asm("v_cvt_pk_bf16_f32 %0, %1, %2" : "=v"(r) : "v"(a), "v"(b)); return r;
}
// legacy 4-slot swizzle (fallback kernels)
__device__ __forceinline__ int swz_off(int r, int s){
  return (r << 6) + (((s ^ (r ^ (r >> 2))) & 3) << 4);
}

__device__ __forceinline__ void gload16(const void* g, void* l) {
  __builtin_amdgcn_global_load_lds(
      (const __attribute__((address_space(1))) unsigned int*)g,
      (__attribute__((address_space(3))) unsigned int*)l, 16, 0, 0);
}

// ---------------- transpose body: fp32 [R][C] -> bf16 col-major [..][R] -------
__device__ __forceinline__ void transpose_body(
    const float* __restrict__ ine, __hip_bfloat16* __restrict__ oute,
    int R, int C, int r0, int c0, int t)
{
  int c = c0 + (t << 2);
  unsigned o[4][16];
  if (c < C) {
    #pragma unroll
    for (int rp = 0; rp < 16; rp++) {
      f32x4 v0 = *(const f32x4*)(ine + (size_t)(r0 + 2*rp)     * C + c);
      f32x4 v1 = *(const f32x4*)(ine + (size_t)(r0 + 2*rp + 1) * C + c);
      #pragma unroll
      for (int j = 0; j < 4; j++) o[j][rp] = cvtpk(v0[j], v1[j]);
    }
  } else {
    #pragma unroll
    for (int j = 0; j < 4; j++)
      #pragma unroll
      for (int rp = 0; rp < 16; rp++) o[j][rp] = 0;
  }
  #pragma unroll
  for (int j = 0; j < 4; j++) {
    u32x4* dst = (u32x4*)(oute + (size_t)(c + j) * R + r0);
    dst[0] = (u32x4){ o[j][0],  o[j][1],  o[j][2],  o[j][3]  };
    dst[1] = (u32x4){ o[j][4],  o[j][5],  o[j][6],  o[j][7]  };
    dst[2] = (u32x4){ o[j][8],  o[j][9],  o[j][10], o[j][11] };
    dst[3] = (u32x4){ o[j][12], o[j][13], o[j][14], o[j][15] };
  }
}

// ---------------- Fused prep: W1 transpose | W2 transpose | router ------------
__global__ __launch_bounds__(256) void prep_k(
    const float* __restrict__ x, const float* __restrict__ Wr,
    const float* __restrict__ br, float* __restrict__ out,
    int* __restrict__ idx, int* __restrict__ cnt_part, float* __restrict__ sum_part,
    __hip_bfloat16* __restrict__ xb,
    const float* __restrict__ W1, __hip_bfloat16* __restrict__ W1t,
    const float* __restrict__ W2, __hip_bfloat16* __restrict__ W2t)
{
  int blk = blockIdx.x, t = threadIdx.x;
  if (blk < 2048) {
    int e = blk >> 9, by = (blk >> 2) & 127, bx = blk & 3;
    transpose_body(W1 + (size_t)e * NH * NH, W1t + (size_t)e * NH * NH,
                   NH, NH, by << 5, bx << 10, t);
    return;
  }
  if (blk < 2560) {
    int bb = blk - 2048;
    int e = bb >> 7, by = bb & 127;
    transpose_body(W2 + (size_t)e * NH * NC, W2t + (size_t)e * NCP * NH,
                   NH, NC, by << 5, 0, t);
    return;
  }
  int b = blk - 2560;
  const float* xr = x + (size_t)b * NH;
  int h0 = t << 4;
  f32x4 v[4];
  #pragma unroll
  for (int j = 0; j < 4; j++) v[j] = *(const f32x4*)(xr + h0 + (j << 2));
  u32x4 ob0 = { cvtpk(v[0][0],v[0][1]), cvtpk(v[0][2],v[0][3]),
                cvtpk(v[1][0],v[1][1]), cvtpk(v[1][2],v[1][3]) };
  u32x4 ob1 = { cvtpk(v[2][0],v[2][1]), cvtpk(v[2][2],v[2][3]),
                cvtpk(v[3][0],v[3][1]), cvtpk(v[3][2],v[3][3]) };
  *(u32x4*)(xb + (size_t)b * NH + h0) = ob0;
  *(u32x4*)(xb + (size_t)b * NH + h0 + 8) = ob1;

  double a0=0, a1=0, a2=0, a3=0;
  #pragma unroll
  for (int i = 0; i < 16; i++) {
    float xv = v[i >> 2][i & 3];
    f32x4 w = *(const f32x4*)(Wr + (size_t)(h0 + i) * 4);
    double xd = (double)xv;
    a0 += xd * (double)w[0]; a1 += xd * (double)w[1];
    a2 += xd * (double)w[2]; a3 += xd * (double)w[3];
  }
  for (int off = 32; off; off >>= 1) {
    a0 += __shfl_down(a0, off); a1 += __shfl_down(a1, off);
    a2 += __shfl_down(a2, off); a3 += __shfl_down(a3, off);
  }
  __shared__ double red[4][4];
  int wid = t >> 6;
  if ((t & 63) == 0) { red[wid][0]=a0; red[wid][1]=a1; red[wid][2]=a2; red[wid][3]=a3; }
  __syncthreads();
  if (t == 0) {
    double l[4];
    for (int e = 0; e < 4; e++)
      l[e] = red[0][e] + red[1][e] + red[2][e] + red[3][e] + (double)br[e];
    int am = 0; double mx = l[0];
    for (int e = 1; e < 4; e++) if (l[e] > mx) { mx = l[e]; am = e; }
    double p[4], s = 0;
    for (int e = 0; e < 4; e++) { p[e] = exp(l[e] - mx); s += p[e]; }
    float* rw = out + (size_t)NB * NC + 1 + (size_t)b * 4;
    int bin = (b & 63) * 4;
    for (int e = 0; e < 4; e++) {
      float pe = (float)(p[e] / s);
      rw[e] = pe;
      atomicAdd(&sum_part[bin + e], pe);
    }
    idx[b] = am;
    atomicAdd(&cnt_part[bin + am], 1);
  }
}

// ---------------- Router (fallback, no xb) ------------------------------------
__global__ __launch_bounds__(256) void router_k(
    const float* __restrict__ x, const float* __restrict__ Wr,
    const float* __restrict__ br, float* __restrict__ out,
    int* __restrict__ idx, int* __restrict__ cnt_part, float* __restrict__ sum_part)
{
  int b = blockIdx.x, t = threadIdx.x;
  const float* xr = x + (size_t)b * NH;
  double a0=0, a1=0, a2=0, a3=0;
  for (int i = 0; i < 16; i++) {
    int h = t + (i << 8);
    float xv = xr[h];
    f32x4 w = *(const f32x4*)(Wr + (size_t)h * 4);
    double xd = (double)xv;
    a0 += xd * (double)w[0]; a1 += xd * (double)w[1];
    a2 += xd * (double)w[2]; a3 += xd * (double)w[3];
  }
  for (int off = 32; off; off >>= 1) {
    a0 += __shfl_down(a0, off); a1 += __shfl_down(a1, off);
    a2 += __shfl_down(a2, off); a3 += __shfl_down(a3, off);
  }
  __shared__ double red[4][4];
  int wid = t >> 6;
  if ((t & 63) == 0) { red[wid][0]=a0; red[wid][1]=a1; red[wid][2]=a2; red[wid][3]=a3; }
  __syncthreads();
  if (t == 0) {
    double l[4];
    for (int e = 0; e < 4; e++)
      l[e] = red[0][e] + red[1][e] + red[2][e] + red[3][e] + (double)br[e];
    int am = 0; double mx = l[0];
    for (int e = 1; e < 4; e++) if (l[e] > mx) { mx = l[e]; am = e; }
    double p[4], s = 0;
    for (int e = 0; e < 4; e++) { p[e] = exp(l[e] - mx); s += p[e]; }
    float* rw = out + (size_t)NB * NC + 1 + (size_t)b * 4;
    int bin = (b & 63) * 4;
    for (int e = 0; e < 4; e++) {
      float pe = (float)(p[e] / s);
      rw[e] = pe;
      atomicAdd(&sum_part[bin + e], pe);
    }
    idx[b] = am;
    atomicAdd(&cnt_part[bin + am], 1);
  }
}

// ---------------- Finalize ----------------------------------------------------
__global__ void finalize_k(const int* __restrict__ cnt_part, const float* __restrict__ sum_part,
                           int* __restrict__ counts, int* __restrict__ offs, float* __restrict__ out)
{
  int t = threadIdx.x;
  __shared__ int cc[4]; __shared__ float ss[4];
  if (t < 4) {
    int c = 0; float s = 0;
    for (int i = 0; i < 64; i++) { c += cnt_part[i*4 + t]; s += sum_part[i*4 + t]; }
    cc[t] = c; ss[t] = s; counts[t] = c;
  }
  __syncthreads();
  if (t == 0) {
    int o = 0; float loss = 0.f;
    for (int e = 0; e < 4; e++) {
      offs[e] = o; o += cc[e];
      loss += ((float)cc[e] / (float)NB) * (ss[e] / (float)NB);
    }
    out[(size_t)NB * NC] = 0.05f * (float)NE * loss;
  }
}

// ---------------- Scatter -----------------------------------------------------
__global__ __launch_bounds__(256) void scatter_k(
    const int* __restrict__ idx, const int* __restrict__ offs,
    int* __restrict__ cursors, int* __restrict__ perm)
{
  int b = blockIdx.x * 256 + threadIdx.x;
  int e = idx[b];
  int lane = threadIdx.x & 63;
  for (int e2 = 0; e2 < 4; e2++) {
    unsigned long long m = __ballot(e == e2);
    if (e == e2) {
      int nbelow = __popcll(m & ((1ULL << lane) - 1ULL));
      int base = 0;
      if (nbelow == 0) base = atomicAdd(&cursors[e2], (int)__popcll(m));
      int src = __ffsll((long long)m) - 1;
      base = __shfl(base, src);
      perm[offs[e2] + base + nbelow] = b;
    }
  }
}

// ---------------- Transpose (fallback-path only) ------------------------------
__global__ __launch_bounds__(256) void transpose_k(
    const float* __restrict__ in, __hip_bfloat16* __restrict__ outp,
    int R, int C, int Cout)
{
  int e = blockIdx.z;
  transpose_body(in + (size_t)e * R * C, outp + (size_t)e * Cout * R,
                 R, C, blockIdx.y << 5, blockIdx.x << 10, threadIdx.x);
}

// ============== 256x256x64 8-phase GEMM1 — R4 quadrant map + sparse waits =====
// H1 = gelu(Xb_gathered @ W1t^T + b1).  512 thr / 8 waves (2m x 4n).
// QUADRANT INVARIANT (the R8 bug): per-wave output rows = mh*128 + wr*64 + ...,
// cols = nq*128 + wc*32 + ...  ->  phase (BB,MH,NQ) reads ONLY A-half MH and
// B-half NQ of buffer BB.  LDS: Abuf[2][32K]@0, Bbuf[2][32K]@64K; half=16K;
// rows 128B, 8x16B slots, phys_slot = logical ^ (row&7) (zero-conflict, R5).
// gload_lds dest linear, src pre-swizzled (rule #21).
// Stage slots (iter tt computes tiles tt,tt+1); each lands one barrier after
// its region's last reader:
//   P1:Bh1(tt+1) P2:Ah1(tt+1) P3:Ah0(tt+2) P4:Bh0(tt+2)+VMW4
//   P5:Bh1(tt+2) P6:Ah1(tt+2) P7:Ah0(tt+3) P8:Bh0(tt+3)+VMW4
// vmcnt(4) at P4/P8 only (T4: never drain in-loop; leaves 2 newest halves in
// flight; in-order completion covers every later consume).  No sched_barrier
// (m141).  setprio around MFMA (T5).

#define DSR8(off) (*(const s16x8*)(lds + (off)))
#define VMW4 asm volatile("s_waitcnt vmcnt(4)" ::: "memory")
#define VMW0 asm volatile("s_waitcnt vmcnt(0)" ::: "memory")
#define NOWAIT do{}while(0)
#define NOSTG  do{}while(0)

#define STG_A(TT,H) do{ \
  gload16(pA[H][0] + (size_t)(TT)*64, lds + ((TT)&1)*32768 + (H)*16384 + wbase); \
  gload16(pA[H][1] + (size_t)(TT)*64, lds + ((TT)&1)*32768 + (H)*16384 + wbase + 1024); \
}while(0)
#define STG_B(TT,H) do{ \
  gload16(pB[H][0] + (size_t)(TT)*64, lds + 65536 + ((TT)&1)*32768 + (H)*16384 + wbase); \
  gload16(pB[H][1] + (size_t)(TT)*64, lds + 65536 + ((TT)&1)*32768 + (H)*16384 + wbase + 1024); \
}while(0)

#define PH8(BB, MH, NQ, STG, WT) do{ \
  s16x8 a_[4][2], b_[2][2]; \
  _Pragma("unroll") \
  for (int mf = 0; mf < 4; mf++) { \
    a_[mf][0] = DSR8((BB)*32768 + (MH)*16384 + arow + mf*2048 + swz0); \
    a_[mf][1] = DSR8((BB)*32768 + (MH)*16384 + arow + mf*2048 + swz1); \
  } \
  _Pragma("unroll") \
  for (int nf = 0; nf < 2; nf++) { \
    b_[nf][0] = DSR8(65536 + (BB)*32768 + (NQ)*16384 + brow + nf*2048 + swz0); \
    b_[nf][1] = DSR8(65536 + (BB)*32768 + (NQ)*16384 + brow + nf*2048 + swz1); \
  } \
  STG; \
  WT; \
  __builtin_amdgcn_s_barrier(); \
  __builtin_amdgcn_s_setprio(1); \
  _Pragma("unroll") \
  for (int mf = 0; mf < 4; mf++) \
    _Pragma("unroll") \
    for (int nf = 0; nf < 2; nf++) { \
      acc[(MH)*2+(NQ)][mf][nf] = __builtin_amdgcn_mfma_f32_16x16x32_bf16(a_[mf][0], b_[nf][0], acc[(MH)*2+(NQ)][mf][nf], 0, 0, 0); \
      acc[(MH)*2+(NQ)][mf][nf] = __builtin_amdgcn_mfma_f32_16x16x32_bf16(a_[mf][1], b_[nf][1], acc[(MH)*2+(NQ)][mf][nf], 0, 0, 0); \
    } \
  __builtin_amdgcn_s_setprio(0); \
  __builtin_amdgcn_s_barrier(); \
}while(0)

__global__ __launch_bounds__(512, 2) void gemm1v2_k(
    const __hip_bfloat16* __restrict__ Ax, const __hip_bfloat16* __restrict__ Bw,
    const float* __restrict__ bias, const int* __restrict__ perm,
    const int* __restrict__ counts, const int* __restrict__ offs,
    __hip_bfloat16* __restrict__ H1out)
{
  int e = blockIdx.z;
  int cnt = counts[e];
  if (cnt == 0) return;
  int m0 = blockIdx.y << 8;
  if (m0 >= cnt) return;
  int seg = offs[e];
  int n0 = blockIdx.x << 8;
  const __hip_bfloat16* Be = Bw + (size_t)e * NH * NH;

  __shared__ __align__(16) char lds[131072];
  __shared__ int rowtok[256];

  int tid = threadIdx.x;
  if (tid < 256) {
    int rr = m0 + tid; if (rr >= cnt) rr = cnt - 1;
    rowtok[tid] = perm[seg + rr];
  }
  __syncthreads();

  int lane = tid & 63, w = tid >> 6;
  int wr = w >> 2, wc = w & 3;          // 2 x 4 wave grid
  int cx = lane & 15, g = lane >> 4;
  int l8 = lane >> 3, l7 = lane & 7;

  // staging: row(h,p) = h*128 + w*16 + p*8 + l8 (row&7 == l8); src pre-swizzled
  int srcoff = (l7 ^ l8) << 3;
  const __hip_bfloat16* pA[2][2];
  const __hip_bfloat16* pB[2][2];
  #pragma unroll
  for (int h = 0; h < 2; h++)
    #pragma unroll
    for (int p = 0; p < 2; p++) {
      int r = h * 128 + w * 16 + p * 8 + l8;
      pA[h][p] = Ax + (size_t)rowtok[r] * NH + srcoff;
      pB[h][p] = Be + (size_t)(n0 + r) * NH + srcoff;
    }
  int wbase = w * 2048;                 // wave's 16-row slice within a half

  // ds_read components: row-in-half(A) = wr*64 + mf*16 + cx (row&7 == cx&7)
  int swz0 = ((0 * 4 + g) ^ (cx & 7)) << 4;
  int swz1 = ((1 * 4 + g) ^ (cx & 7)) << 4;
  int arow = (wr * 64 + cx) * 128;
  int brow = (wc * 32 + cx) * 128;

  f32x4 acc[4][4][2] = {};              // [MH*2+NQ][mf][nf]

  const int NT = NH / 64;               // 64 K-tiles

  // prologue: tile0 full + tile1 half-0s; VMW4 -> tile0 resident, (1,0)s fly
  STG_A(0,0); STG_B(0,0); STG_B(0,1); STG_A(0,1); STG_A(1,0); STG_B(1,0);
  VMW4;
  __builtin_amdgcn_s_barrier();

  #pragma unroll 1
  for (int tt = 0; tt <= NT - 4; tt += 2) {
    PH8(0, 0, 0, STG_B(tt+1,1), NOWAIT);
    PH8(0, 0, 1, STG_A(tt+1,1), NOWAIT);
    PH8(0, 1, 0, STG_A(tt+2,0), NOWAIT);
    PH8(0, 1, 1, STG_B(tt+2,0), VMW4);
    PH8(1, 0, 0, STG_B(tt+2,1), NOWAIT);
    PH8(1, 0, 1, STG_A(tt+2,1), NOWAIT);
    PH8(1, 1, 0, STG_A(tt+3,0), NOWAIT);
    PH8(1, 1, 1, STG_B(tt+3,0), VMW4);
  }
  // final iter (tiles NT-2, NT-1): stage NT-1's half-1s, drain all at P4
  PH8(0, 0, 0, STG_B(NT-1,1), NOWAIT);
  PH8(0, 0, 1, STG_A(NT-1,1), NOWAIT);
  PH8(0, 1, 0, NOSTG, NOWAIT);
  PH8(0, 1, 1, NOSTG, VMW0);
  PH8(1, 0, 0, NOSTG, NOWAIT);
  PH8(1, 0, 1, NOSTG, NOWAIT);
  PH8(1, 1, 0, NOSTG, NOWAIT);
  PH8(1, 1, 1, NOSTG, NOWAIT);

  // epilogue: row = mh*128 + wr*64 + mf*16 + g*4 + i; col = nq*128 + wc*32 + nf*16 + cx
  const float* be_ = bias + (size_t)e * NH;
  #pragma unroll
  for (int mh = 0; mh < 2; mh++)
  #pragma unroll
  for (int nq = 0; nq < 2; nq++)
  #pragma unroll
  for (int nf = 0; nf < 2; nf++) {
    int n = n0 + nq * 128 + wc * 32 + nf * 16 + cx;
    float bv = be_[n];
    #pragma unroll
    for (int mf = 0; mf < 4; mf++) {
      f32x4 vacc = acc[mh*2+nq][mf][nf];
      #pragma unroll
      for (int i = 0; i < 4; i++) {
        int mrow = mh * 128 + wr * 64 + mf * 16 + g * 4 + i;
        int mseg = m0 + mrow;
        if (mseg < cnt) {
          float u = vacc[i] + bv;
          float th = tanhf(0.79788456080286535588f * (u + 0.044715f * u * u * u));
          float hv = 0.5f * u * (1.0f + th);
          H1out[(size_t)(seg + mseg) * NH + n] = __float2bfloat16(hv);
        }
      }
    }
  }
}

// ========== 128x128x64 single-buffer GEMM (R6-proven; used for gemm2) =========
#define DSR(off) (*(const s16x8*)(lds + (off)))

template<int MODE>
__global__ __launch_bounds__(256, 3) void gemmsb_k(
    const __hip_bfloat16* __restrict__ Ax, const __hip_bfloat16* __restrict__ Bw,
    const float* __restrict__ bias, const int* __restrict__ perm,
    const int* __restrict__ counts, const int* __restrict__ offs,
    __hip_bfloat16* __restrict__ H1out, float* __restrict__ out)
{
  int e = blockIdx.z;
  int cnt = counts[e];
  if (cnt == 0) return;
  int m0 = blockIdx.y << 7;
  if (m0 >= cnt) return;
  int seg = offs[e];
  int n0 = blockIdx.x << 7;
  const __hip_bfloat16* Be = Bw + (size_t)e * (size_t)(MODE == 0 ? NH : NCP) * NH;

  __shared__ __align__(16) char lds[32768];
  __shared__ int rowtok[128];

  int tid = threadIdx.x;
  if (tid < 128) {
    int rr = m0 + tid; if (rr >= cnt) rr = cnt - 1;
    rowtok[tid] = perm[seg + rr];
  }
  __syncthreads();

  int lane = tid & 63, w = tid >> 6;
  int wr = w >> 1, wc = w & 1;
  int cx = lane & 15, g = lane >> 4;
  int l8 = lane >> 3, l7 = lane & 7;

  int srcoff = (l7 ^ l8) << 3;
  const __hip_bfloat16* pA[4];
  const __hip_bfloat16* pB[4];
  #pragma unroll
  for (int i = 0; i < 4; i++) {
    int r = w * 32 + i * 8 + l8;
    if constexpr (MODE == 0) {
      pA[i] = Ax + (size_t)rowtok[r] * NH + srcoff;
    } else {
      int rr = m0 + r; if (rr >= cnt) rr = cnt - 1;
      pA[i] = Ax + (size_t)(seg + rr) * NH + srcoff;
    }
    pB[i] = Be + (size_t)(n0 + r) * NH + srcoff;
  }
  int wst = w * 4096;

  int swz0 = ((0 * 4 + g) ^ (cx & 7)) << 4;
  int swz1 = ((1 * 4 + g) ^ (cx & 7)) << 4;
  int arow = (wr * 64 + cx) * 128;
  int brow = (wc * 64 + cx) * 128;

  f32x4 acc[4][4] = {};

  const int NT = NH / 64;

  for (int t = 0; t < NT; t++) {
    gload16(pA[0] + (size_t)t*64, lds + wst);
    gload16(pA[1] + (size_t)t*64, lds + wst + 1024);
    gload16(pA[2] + (size_t)t*64, lds + wst + 2048);
    gload16(pA[3] + (size_t)t*64, lds + wst + 3072);
    gload16(pB[0] + (size_t)t*64, lds + 16384 + wst);
    gload16(pB[1] + (size_t)t*64, lds + 16384 + wst + 1024);
    gload16(pB[2] + (size_t)t*64, lds + 16384 + wst + 2048);
    gload16(pB[3] + (size_t)t*64, lds + 16384 + wst + 3072);
    __syncthreads();

    s16x8 a0_[4], b0_[4], a1_[4], b1_[4];
    #pragma unroll
    for (int mf = 0; mf < 4; mf++) a0_[mf] = DSR(arow + mf*2048 + swz0);
    #pragma unroll
    for (int nf = 0; nf < 4; nf++) b0_[nf] = DSR(16384 + brow + nf*2048 + swz0);
    #pragma unroll
    for (int mf = 0; mf < 4; mf++)
      #pragma unroll
      for (int nf = 0; nf < 4; nf++)
        acc[mf][nf] = __builtin_amdgcn_mfma_f32_16x16x32_bf16(a0_[mf], b0_[nf], acc[mf][nf], 0, 0, 0);
    #pragma unroll
    for (int mf = 0; mf < 4; mf++) a1_[mf] = DSR(arow + mf*2048 + swz1);
    #pragma unroll
    for (int nf = 0; nf < 4; nf++) b1_[nf] = DSR(16384 + brow + nf*2048 + swz1);
    #pragma unroll
    for (int mf = 0; mf < 4; mf++)
      #pragma unroll
      for (int nf = 0; nf < 4; nf++)
        acc[mf][nf] = __builtin_amdgcn_mfma_f32_16x16x32_bf16(a1_[mf], b1_[nf], acc[mf][nf], 0, 0, 0);
    __syncthreads();
  }

  #pragma unroll
  for (int nf = 0; nf < 4; nf++) {
    int n = n0 + wc * 64 + nf * 16 + cx;
    if (MODE == 0 || n < NC) {
      float bv = bias[(size_t)e * (MODE == 0 ? NH : NC) + n];
      #pragma unroll
      for (int mf = 0; mf < 4; mf++) {
        f32x4 vacc = acc[mf][nf];
        #pragma unroll
        for (int i = 0; i < 4; i++) {
          int mrow = wr * 64 + mf * 16 + g * 4 + i;
          int mseg = m0 + mrow;
          if (mseg < cnt) {
            float u = vacc[i] + bv;
            if constexpr (MODE == 0) {
              float th = tanhf(0.79788456080286535588f * (u + 0.044715f * u * u * u));
              float hv = 0.5f * u * (1.0f + th);
              H1out[(size_t)(seg + mseg) * NH + n] = __float2bfloat16(hv);
            } else {
              int tok = rowtok[mrow];
              out[(size_t)tok * NC + n] = u;
            }
          }
        }
      }
    }
  }
}

// ================= Fallback kernels (Round-1, proven, ws-light) ===============
__global__ __launch_bounds__(256) void gemm1_k(
    const float* __restrict__ x, const float* __restrict__ W1,
    const float* __restrict__ b1, const int* __restrict__ perm,
    const int* __restrict__ counts, const int* __restrict__ offs,
    __hip_bfloat16* __restrict__ H1)
{
  int e = blockIdx.z;
  int cnt = counts[e];
  int m0 = blockIdx.y << 7;
  if (m0 >= cnt) return;
  int seg = offs[e];
  int n0 = blockIdx.x << 7;
  const float* W1e = W1 + (size_t)e * NH * NH;

  __shared__ __align__(16) char As[128*32*2];
  __shared__ __align__(16) char Bs[128*32*2];
  __shared__ int rowtok[128];

  int t = threadIdx.x;
  if (t < 128) {
    int rr = m0 + t; if (rr >= cnt) rr = cnt - 1;
    rowtok[t] = perm[seg + rr];
  }
  __syncthreads();

  int ar0 = t >> 2, as_ = t & 3;
  int ar1 = ar0 + 64;
  const float* asrc0 = x + (size_t)rowtok[ar0] * NH + (as_ << 3);
  const float* asrc1 = x + (size_t)rowtok[ar1] * NH + (as_ << 3);
  int aw0 = swz_off(ar0, as_), aw1 = swz_off(ar1, as_);
  int bnc = t & 31, bkp = t >> 5;
  const float* bsrc0 = W1e + (size_t)(bkp << 1) * NH + n0 + (bnc << 2);
  const float* bsrc1 = bsrc0 + (size_t)16 * NH;

  f32x4 acc[4][4] = {};

  int lane = t & 63, wid = t >> 6;
  int wm = (wid >> 1) << 6, wn = (wid & 1) << 6;
  int g = lane >> 4, cx = lane & 15;
  int aoff[4], boff[4];
  #pragma unroll
  for (int f = 0; f < 4; f++) {
    aoff[f] = swz_off(wm + (f << 4) + cx, g);
    boff[f] = swz_off(wn + (f << 4) + cx, g);
  }

  for (int kt = 0; kt < NH; kt += 32) {
    {
      f32x4 v0 = *(const f32x4*)(asrc0 + kt);
      f32x4 v1 = *(const f32x4*)(asrc0 + kt + 4);
      u32x4 wv = { cvtpk(v0[0],v0[1]), cvtpk(v0[2],v0[3]), cvtpk(v1[0],v1[1]), cvtpk(v1[2],v1[3]) };
      *(u32x4*)(As + aw0) = wv;
      f32x4 u0 = *(const f32x4*)(asrc1 + kt);
      f32x4 u1 = *(const f32x4*)(asrc1 + kt + 4);
      u32x4 w2 = { cvtpk(u0[0],u0[1]), cvtpk(u0[2],u0[3]), cvtpk(u1[0],u1[1]), cvtpk(u1[2],u1[3]) };
      *(u32x4*)(As + aw1) = w2;
    }
    {
      const float* p0 = bsrc0 + (size_t)kt * NH;
      f32x4 rr0 = *(const f32x4*)p0;
      f32x4 rr1 = *(const f32x4*)(p0 + NH);
      int kp = bkp, sl = kp >> 2, sub = (kp & 3) << 2;
      #pragma unroll
      for (int j = 0; j < 4; j++) {
        int n = (bnc << 2) + j;
        *(unsigned*)(Bs + (n << 6) + (((sl ^ (n ^ (n >> 2))) & 3) << 4) + sub) = cvtpk(rr0[j], rr1[j]);
      }
      const float* p1 = bsrc1 + (size_t)kt * NH;
      f32x4 q0 = *(const f32x4*)p1;
      f32x4 q1 = *(const f32x4*)(p1 + NH);
      kp = bkp + 8; sl = kp >> 2; sub = (kp & 3) << 2;
      #pragma unroll
      for (int j = 0; j < 4; j++) {
        int n = (bnc << 2) + j;
        *(unsigned*)(Bs + (n << 6) + (((sl ^ (n ^ (n >> 2))) & 3) << 4) + sub) = cvtpk(q0[j], q1[j]);
      }
    }
    __syncthreads();
    s16x8 af[4], bfr[4];
    #pragma unroll
    for (int f = 0; f < 4; f++) {
      af[f]  = *(const s16x8*)(As + aoff[f]);
      bfr[f] = *(const s16x8*)(Bs + boff[f]);
    }
    #pragma unroll
    for (int mf = 0; mf < 4; mf++)
      #pragma unroll
      for (int nf = 0; nf < 4; nf++)
        acc[mf][nf] = __builtin_amdgcn_mfma_f32_16x16x32_bf16(af[mf], bfr[nf], acc[mf][nf], 0, 0, 0);
    __syncthreads();
  }

  const float* b1e = b1 + (size_t)e * NH;
  #pragma unroll
  for (int nf = 0; nf < 4; nf++) {
    int n = n0 + wn + (nf << 4) + cx;
    float bv = b1e[n];
    #pragma unroll
    for (int mf = 0; mf < 4; mf++) {
      #pragma unroll
      for (int i = 0; i < 4; i++) {
        int mseg = m0 + wm + (mf << 4) + (g << 2) + i;
        if (mseg < cnt) {
          float u = acc[mf][nf][i] + bv;
          float th = tanhf(0.79788456080286535588f * (u + 0.044715f * u * u * u));
          float hv = 0.5f * u * (1.0f + th);
          H1[(size_t)(seg + mseg) * NH + n] = __float2bfloat16(hv);
        }
      }
    }
  }
}

__global__ __launch_bounds__(256) void gemm2_k(
    const __hip_bfloat16* __restrict__ H1, const float* __restrict__ W2,
    const float* __restrict__ b2, const int* __restrict__ perm,
    const int* __restrict__ counts, const int* __restrict__ offs,
    float* __restrict__ out)
{
  int e = blockIdx.z;
  int cnt = counts[e];
  int m0 = blockIdx.y << 7;
  if (m0 >= cnt) return;
  int seg = offs[e];
  int n0 = blockIdx.x << 7;
  const float* W2e = W2 + (size_t)e * NH * NC;

  __shared__ __align__(16) char As[128*32*2];
  __shared__ __align__(16) char Bs[128*32*2];
  __shared__ int rowtok[128];

  int t = threadIdx.x;
  if (t < 128) {
    int rr = m0 + t; if (rr >= cnt) rr = cnt - 1;
    rowtok[t] = perm[seg + rr];
  }
  __syncthreads();

  int ar0 = t >> 2, as_ = t & 3;
  int ar1 = ar0 + 64;
  int rA0 = m0 + ar0; if (rA0 >= cnt) rA0 = cnt - 1;
  int rA1 = m0 + ar1; if (rA1 >= cnt) rA1 = cnt - 1;
  const __hip_bfloat16* asrc0 = H1 + (size_t)(seg + rA0) * NH + (as_ << 3);
  const __hip_bfloat16* asrc1 = H1 + (size_t)(seg + rA1) * NH + (as_ << 3);
  int aw0 = swz_off(ar0, as_), aw1 = swz_off(ar1, as_);

  int bnc = t & 31, bkp = t >> 5;
  int col = n0 + (bnc << 2);
  bool bvalid = col < NC;
  const float* bsrc0 = W2e + (size_t)(bkp << 1) * NC + col;
  const float* bsrc1 = bsrc0 + (size_t)16 * NC;

  f32x4 acc[4][4] = {};

  int lane = t & 63, wid = t >> 6;
  int wm = (wid >> 1) << 6, wn = (wid & 1) << 6;
  int g = lane >> 4, cx = lane & 15;
  int aoff[4], boff[4];
  #pragma unroll
  for (int f = 0; f < 4; f++) {
    aoff[f] = swz_off(wm + (f << 4) + cx, g);
    boff[f] = swz_off(wn + (f << 4) + cx, g);
  }

  for (int kt = 0; kt < NH; kt += 32) {
    {
      *(u32x4*)(As + aw0) = *(const u32x4*)(asrc0 + kt);
      *(u32x4*)(As + aw1) = *(const u32x4*)(asrc1 + kt);
    }
    {
      f32x4 rr0 = {}, rr1 = {}, q0 = {}, q1 = {};
      if (bvalid) {
        const float* p0 = bsrc0 + (size_t)kt * NC;
        rr0 = *(const f32x4*)p0; rr1 = *(const f32x4*)(p0 + NC);
        const float* p1 = bsrc1 + (size_t)kt * NC;
        q0 = *(const f32x4*)p1; q1 = *(const f32x4*)(p1 + NC);
      }
      int kp = bkp, sl = kp >> 2, sub = (kp & 3) << 2;
      #pragma unroll
      for (int j = 0; j < 4; j++) {
        int n = (bnc << 2) + j;
        *(unsigned*)(Bs + (n << 6) + (((sl ^ (n ^ (n >> 2))) & 3) << 4) + sub) = cvtpk(rr0[j], rr1[j]);
      }
      kp = bkp + 8; sl = kp >> 2; sub = (kp & 3) << 2;
      #pragma unroll
      for (int j = 0; j < 4; j++) {
        int n = (bnc << 2) + j;
        *(unsigned*)(Bs + (n << 6) + (((sl ^ (n ^ (n >> 2))) & 3) << 4) + sub) = cvtpk(q0[j], q1[j]);
      }
    }
    __syncthreads();
    s16x8 af[4], bfr[4];
    #pragma unroll
    for (int f = 0; f < 4; f++) {
      af[f]  = *(const s16x8*)(As + aoff[f]);
      bfr[f] = *(const s16x8*)(Bs + boff[f]);
    }
    #pragma unroll
    for (int mf = 0; mf < 4; mf++)
      #pragma unroll
      for (int nf = 0; nf < 4; nf++)
        acc[mf][nf] = __builtin_amdgcn_mfma_f32_16x16x32_bf16(af[mf], bfr[nf], acc[mf][nf], 0, 0, 0);
    __syncthreads();
  }

  const float* b2e = b2 + (size_t)e * NC;
  #pragma unroll
  for (int nf = 0; nf < 4; nf++) {
    int n = n0 + wn + (nf << 4) + cx;
    if (n < NC) {
      float bv = b2e[n];
      #pragma unroll
      for (int mf = 0; mf < 4; mf++) {
        #pragma unroll
        for (int i = 0; i < 4; i++) {
          int mseg = m0 + wm + (mf << 4) + (g << 2) + i;
          if (mseg < cnt) {
            int tok = rowtok[wm + (mf << 4) + (g << 2) + i];
            out[(size_t)tok * NC + n] = acc[mf][nf][i] + bv;
          }
        }
      }
    }
  }
}

extern "C" void kernel_launch(void* const* d_in, const int* in_sizes, int n_in,
                              void* d_out, int out_size, void* d_ws, size_t ws_size,
                              hipStream_t stream) {
  const float* x  = (const float*)d_in[0];
  const float* Wr = (const float*)d_in[1];
  const float* br = (const float*)d_in[2];
  const float* W1 = (const float*)d_in[3];
  const float* b1 = (const float*)d_in[4];
  const float* W2 = (const float*)d_in[5];
  const float* b2 = (const float*)d_in[6];
  float* out = (float*)d_out;

  char* ws = (char*)d_ws;
  const size_t SZ_XB  = (size_t)NB * NH * 2;
  const size_t SZ_H1  = (size_t)NB * NH * 2;
  const size_t SZ_W1T = (size_t)NE * NH * NH * 2;
  const size_t SZ_W2T = (size_t)NE * NCP * NH * 2;
  const size_t need = SZ_XB + SZ_H1 + SZ_W1T + SZ_W2T + (size_t)NB*4*2 + 4096;

  if (ws_size >= need) {
    size_t o = 0;
    __hip_bfloat16* xb  = (__hip_bfloat16*)(ws + o); o += SZ_XB;
    __hip_bfloat16* H1  = (__hip_bfloat16*)(ws + o); o += SZ_H1;
    __hip_bfloat16* W1t = (__hip_bfloat16*)(ws + o); o += SZ_W1T;
    __hip_bfloat16* W2t = (__hip_bfloat16*)(ws + o); o += SZ_W2T;
    int* idx  = (int*)(ws + o); o += (size_t)NB * 4;
    int* perm = (int*)(ws + o); o += (size_t)NB * 4;
    char* small = ws + o;
    int*   cursors  = (int*)(small);
    int*   counts   = (int*)(small + 16);
    int*   offs     = (int*)(small + 32);
    int*   cnt_part = (int*)(small + 64);
    float* sum_part = (float*)(small + 64 + 1024);

    hipMemsetAsync(small, 0, 64 + 2048, stream);
    prep_k<<<10752, 256, 0, stream>>>(x, Wr, br, out, idx, cnt_part, sum_part, xb,
                                      W1, W1t, W2, W2t);
    finalize_k<<<1, 64, 0, stream>>>(cnt_part, sum_part, counts, offs, out);
    scatter_k<<<NB / 256, 256, 0, stream>>>(idx, offs, cursors, perm);
    gemm1v2_k<<<dim3(16, 32, 4), 512, 0, stream>>>(xb, W1t, b1, perm, counts, offs, H1);
    gemmsb_k<1><<<dim3(8, 64, 4), 256, 0, stream>>>(H1, W2t, b2, perm, counts, offs, nullptr, out);
  } else {
    __hip_bfloat16* H1 = (__hip_bfloat16*)ws;
    size_t o = (size_t)NB * NH * 2;
    int* idx  = (int*)(ws + o); o += (size_t)NB * 4;
    int* perm = (int*)(ws + o); o += (size_t)NB * 4;
    char* small = ws + o;
    int*   cursors  = (int*)(small);
    int*   counts   = (int*)(small + 16);
    int*   offs     = (int*)(small + 32);
    int*   cnt_part = (int*)(small + 64);
    float* sum_part = (float*)(small + 64 + 1024);

    hipMemsetAsync(small, 0, 64 + 2048, stream);
    router_k<<<NB, 256, 0, stream>>>(x, Wr, br, out, idx, cnt_part, sum_part);
    finalize_k<<<1, 64, 0, stream>>>(cnt_part, sum_part, counts, offs, out);
    scatter_k<<<NB / 256, 256, 0, stream>>>(idx, offs, cursors, perm);
    gemm1_k<<<dim3(32, 64, 4), 256, 0, stream>>>(x, W1, b1, perm, counts, offs, H1);
    gemm2_k<<<dim3(8, 64, 4), 256, 0, stream>>>(H1, W2, b2, perm, counts, offs, out);
  }
}

// Round 10
// 723.639 us; speedup vs baseline: 1.2644x; 1.2644x over previous
//
#include <hip/hip_runtime.h>
#include <hip/hip_bf16.h>

#define NB 8192
#define NH 4096
#define NC 1000
#define NE 4
#define NCP 1024   // padded N for gemm2

typedef __attribute__((ext_vector_type(4))) float f32x4;
typedef __attribute__((ext_vector_type(8))) short s16x8;
typedef __attribute__((ext_vector_type(4))) unsigned int u32x4;

__device__ __forceinline__ unsigned cvtpk(float a, float b){
  unsigned r; asm("v_cvt_pk_bf16_f32 %0, %1, %2" : "=v"(r) : "v"(a), "v"(b)); return r;
}
// legacy 4-slot swizzle (fallback kernels)
__device__ __forceinline__ int swz_off(int r, int s){
  return (r << 6) + (((s ^ (r ^ (r >> 2))) & 3) << 4);
}

__device__ __forceinline__ void gload16(const void* g, void* l) {
  __builtin_amdgcn_global_load_lds(
      (const __attribute__((address_space(1))) unsigned int*)g,
      (__attribute__((address_space(3))) unsigned int*)l, 16, 0, 0);
}

// ---------------- transpose body: fp32 [R][C] -> bf16 col-major [..][R] -------
__device__ __forceinline__ void transpose_body(
    const float* __restrict__ ine, __hip_bfloat16* __restrict__ oute,
    int R, int C, int r0, int c0, int t)
{
  int c = c0 + (t << 2);
  unsigned o[4][16];
  if (c < C) {
    #pragma unroll
    for (int rp = 0; rp < 16; rp++) {
      f32x4 v0 = *(const f32x4*)(ine + (size_t)(r0 + 2*rp)     * C + c);
      f32x4 v1 = *(const f32x4*)(ine + (size_t)(r0 + 2*rp + 1) * C + c);
      #pragma unroll
      for (int j = 0; j < 4; j++) o[j][rp] = cvtpk(v0[j], v1[j]);
    }
  } else {
    #pragma unroll
    for (int j = 0; j < 4; j++)
      #pragma unroll
      for (int rp = 0; rp < 16; rp++) o[j][rp] = 0;
  }
  #pragma unroll
  for (int j = 0; j < 4; j++) {
    u32x4* dst = (u32x4*)(oute + (size_t)(c + j) * R + r0);
    dst[0] = (u32x4){ o[j][0],  o[j][1],  o[j][2],  o[j][3]  };
    dst[1] = (u32x4){ o[j][4],  o[j][5],  o[j][6],  o[j][7]  };
    dst[2] = (u32x4){ o[j][8],  o[j][9],  o[j][10], o[j][11] };
    dst[3] = (u32x4){ o[j][12], o[j][13], o[j][14], o[j][15] };
  }
}

// ---------------- Fused prep: W1 transpose | W2 transpose | router ------------
// blocks [0,2048): W1->W1t; [2048,2560): W2->W2t; [2560,10752): router+xb.
// Independent memory-bound work in one launch fills the GPU (R7: helped).
__global__ __launch_bounds__(256) void prep_k(
    const float* __restrict__ x, const float* __restrict__ Wr,
    const float* __restrict__ br, float* __restrict__ out,
    int* __restrict__ idx, int* __restrict__ cnt_part, float* __restrict__ sum_part,
    __hip_bfloat16* __restrict__ xb,
    const float* __restrict__ W1, __hip_bfloat16* __restrict__ W1t,
    const float* __restrict__ W2, __hip_bfloat16* __restrict__ W2t)
{
  int blk = blockIdx.x, t = threadIdx.x;
  if (blk < 2048) {
    int e = blk >> 9, by = (blk >> 2) & 127, bx = blk & 3;
    transpose_body(W1 + (size_t)e * NH * NH, W1t + (size_t)e * NH * NH,
                   NH, NH, by << 5, bx << 10, t);
    return;
  }
  if (blk < 2560) {
    int bb = blk - 2048;
    int e = bb >> 7, by = bb & 127;
    transpose_body(W2 + (size_t)e * NH * NC, W2t + (size_t)e * NCP * NH,
                   NH, NC, by << 5, 0, t);
    return;
  }
  int b = blk - 2560;
  const float* xr = x + (size_t)b * NH;
  int h0 = t << 4;
  f32x4 v[4];
  #pragma unroll
  for (int j = 0; j < 4; j++) v[j] = *(const f32x4*)(xr + h0 + (j << 2));
  u32x4 ob0 = { cvtpk(v[0][0],v[0][1]), cvtpk(v[0][2],v[0][3]),
                cvtpk(v[1][0],v[1][1]), cvtpk(v[1][2],v[1][3]) };
  u32x4 ob1 = { cvtpk(v[2][0],v[2][1]), cvtpk(v[2][2],v[2][3]),
                cvtpk(v[3][0],v[3][1]), cvtpk(v[3][2],v[3][3]) };
  *(u32x4*)(xb + (size_t)b * NH + h0) = ob0;
  *(u32x4*)(xb + (size_t)b * NH + h0 + 8) = ob1;

  double a0=0, a1=0, a2=0, a3=0;
  #pragma unroll
  for (int i = 0; i < 16; i++) {
    float xv = v[i >> 2][i & 3];
    f32x4 w = *(const f32x4*)(Wr + (size_t)(h0 + i) * 4);
    double xd = (double)xv;
    a0 += xd * (double)w[0]; a1 += xd * (double)w[1];
    a2 += xd * (double)w[2]; a3 += xd * (double)w[3];
  }
  for (int off = 32; off; off >>= 1) {
    a0 += __shfl_down(a0, off); a1 += __shfl_down(a1, off);
    a2 += __shfl_down(a2, off); a3 += __shfl_down(a3, off);
  }
  __shared__ double red[4][4];
  int wid = t >> 6;
  if ((t & 63) == 0) { red[wid][0]=a0; red[wid][1]=a1; red[wid][2]=a2; red[wid][3]=a3; }
  __syncthreads();
  if (t == 0) {
    double l[4];
    for (int e = 0; e < 4; e++)
      l[e] = red[0][e] + red[1][e] + red[2][e] + red[3][e] + (double)br[e];
    int am = 0; double mx = l[0];
    for (int e = 1; e < 4; e++) if (l[e] > mx) { mx = l[e]; am = e; }
    double p[4], s = 0;
    for (int e = 0; e < 4; e++) { p[e] = exp(l[e] - mx); s += p[e]; }
    float* rw = out + (size_t)NB * NC + 1 + (size_t)b * 4;
    int bin = (b & 63) * 4;
    for (int e = 0; e < 4; e++) {
      float pe = (float)(p[e] / s);
      rw[e] = pe;
      atomicAdd(&sum_part[bin + e], pe);
    }
    idx[b] = am;
    atomicAdd(&cnt_part[bin + am], 1);
  }
}

// ---------------- Router (fallback, no xb) ------------------------------------
__global__ __launch_bounds__(256) void router_k(
    const float* __restrict__ x, const float* __restrict__ Wr,
    const float* __restrict__ br, float* __restrict__ out,
    int* __restrict__ idx, int* __restrict__ cnt_part, float* __restrict__ sum_part)
{
  int b = blockIdx.x, t = threadIdx.x;
  const float* xr = x + (size_t)b * NH;
  double a0=0, a1=0, a2=0, a3=0;
  for (int i = 0; i < 16; i++) {
    int h = t + (i << 8);
    float xv = xr[h];
    f32x4 w = *(const f32x4*)(Wr + (size_t)h * 4);
    double xd = (double)xv;
    a0 += xd * (double)w[0]; a1 += xd * (double)w[1];
    a2 += xd * (double)w[2]; a3 += xd * (double)w[3];
  }
  for (int off = 32; off; off >>= 1) {
    a0 += __shfl_down(a0, off); a1 += __shfl_down(a1, off);
    a2 += __shfl_down(a2, off); a3 += __shfl_down(a3, off);
  }
  __shared__ double red[4][4];
  int wid = t >> 6;
  if ((t & 63) == 0) { red[wid][0]=a0; red[wid][1]=a1; red[wid][2]=a2; red[wid][3]=a3; }
  __syncthreads();
  if (t == 0) {
    double l[4];
    for (int e = 0; e < 4; e++)
      l[e] = red[0][e] + red[1][e] + red[2][e] + red[3][e] + (double)br[e];
    int am = 0; double mx = l[0];
    for (int e = 1; e < 4; e++) if (l[e] > mx) { mx = l[e]; am = e; }
    double p[4], s = 0;
    for (int e = 0; e < 4; e++) { p[e] = exp(l[e] - mx); s += p[e]; }
    float* rw = out + (size_t)NB * NC + 1 + (size_t)b * 4;
    int bin = (b & 63) * 4;
    for (int e = 0; e < 4; e++) {
      float pe = (float)(p[e] / s);
      rw[e] = pe;
      atomicAdd(&sum_part[bin + e], pe);
    }
    idx[b] = am;
    atomicAdd(&cnt_part[bin + am], 1);
  }
}

// ---------------- Finalize ----------------------------------------------------
__global__ void finalize_k(const int* __restrict__ cnt_part, const float* __restrict__ sum_part,
                           int* __restrict__ counts, int* __restrict__ offs, float* __restrict__ out)
{
  int t = threadIdx.x;
  __shared__ int cc[4]; __shared__ float ss[4];
  if (t < 4) {
    int c = 0; float s = 0;
    for (int i = 0; i < 64; i++) { c += cnt_part[i*4 + t]; s += sum_part[i*4 + t]; }
    cc[t] = c; ss[t] = s; counts[t] = c;
  }
  __syncthreads();
  if (t == 0) {
    int o = 0; float loss = 0.f;
    for (int e = 0; e < 4; e++) {
      offs[e] = o; o += cc[e];
      loss += ((float)cc[e] / (float)NB) * (ss[e] / (float)NB);
    }
    out[(size_t)NB * NC] = 0.05f * (float)NE * loss;
  }
}

// ---------------- Scatter -----------------------------------------------------
__global__ __launch_bounds__(256) void scatter_k(
    const int* __restrict__ idx, const int* __restrict__ offs,
    int* __restrict__ cursors, int* __restrict__ perm)
{
  int b = blockIdx.x * 256 + threadIdx.x;
  int e = idx[b];
  int lane = threadIdx.x & 63;
  for (int e2 = 0; e2 < 4; e2++) {
    unsigned long long m = __ballot(e == e2);
    if (e == e2) {
      int nbelow = __popcll(m & ((1ULL << lane) - 1ULL));
      int base = 0;
      if (nbelow == 0) base = atomicAdd(&cursors[e2], (int)__popcll(m));
      int src = __ffsll((long long)m) - 1;
      base = __shfl(base, src);
      perm[offs[e2] + base + nbelow] = b;
    }
  }
}

// ---------------- Transpose (fallback-path only) ------------------------------
__global__ __launch_bounds__(256) void transpose_k(
    const float* __restrict__ in, __hip_bfloat16* __restrict__ outp,
    int R, int C, int Cout)
{
  int e = blockIdx.z;
  transpose_body(in + (size_t)e * R * C, outp + (size_t)e * Cout * R,
                 R, C, blockIdx.y << 5, blockIdx.x << 10, threadIdx.x);
}

// ========== 128x128x64 single-buffer GEMM, compiler-scheduled (R6-proven) =====
// MODE 0: H1 = gelu(Xb_gathered @ W1t^T + b1)   (A = xb via perm, out bf16)
// MODE 1: out_scattered = H1 @ W2t^T + b2       (A = H1 rows, out fp32 scatter)
// LDS 32KB; zero bank conflicts (R5-measured: 8x16B slots, phys = logical ^
// (row&7), gload_lds dest linear + src pre-swizzled, rule #21).  NO manual
// scheduling (m141/R5), NO XCD swizzle (R7: FETCH +75%, -14us).  741 TF @R6.

#define DSR(off) (*(const s16x8*)(lds + (off)))

template<int MODE>
__global__ __launch_bounds__(256, 4) void gemmsb_k(
    const __hip_bfloat16* __restrict__ Ax, const __hip_bfloat16* __restrict__ Bw,
    const float* __restrict__ bias, const int* __restrict__ perm,
    const int* __restrict__ counts, const int* __restrict__ offs,
    __hip_bfloat16* __restrict__ H1out, float* __restrict__ out)
{
  int e = blockIdx.z;
  int cnt = counts[e];
  if (cnt == 0) return;
  int m0 = blockIdx.y << 7;
  if (m0 >= cnt) return;
  int seg = offs[e];
  int n0 = blockIdx.x << 7;
  const __hip_bfloat16* Be = Bw + (size_t)e * (size_t)(MODE == 0 ? NH : NCP) * NH;

  __shared__ __align__(16) char lds[32768];
  __shared__ int rowtok[128];

  int tid = threadIdx.x;
  if (tid < 128) {
    int rr = m0 + tid; if (rr >= cnt) rr = cnt - 1;
    rowtok[tid] = perm[seg + rr];
  }
  __syncthreads();

  int lane = tid & 63, w = tid >> 6;
  int wr = w >> 1, wc = w & 1;          // 2 x 2 wave grid, wave out = 64x64
  int cx = lane & 15, g = lane >> 4;
  int l8 = lane >> 3, l7 = lane & 7;

  // ---- staging pointers (src pre-swizzled; LDS dest wave-uniform base) ----
  int srcoff = (l7 ^ l8) << 3;          // logical slot = phys ^ (row&7); row&7 == l8
  const __hip_bfloat16* pA[4];
  const __hip_bfloat16* pB[4];
  #pragma unroll
  for (int i = 0; i < 4; i++) {
    int r = w * 32 + i * 8 + l8;        // row in 128-row tile
    if constexpr (MODE == 0) {
      pA[i] = Ax + (size_t)rowtok[r] * NH + srcoff;
    } else {
      int rr = m0 + r; if (rr >= cnt) rr = cnt - 1;
      pA[i] = Ax + (size_t)(seg + rr) * NH + srcoff;
    }
    pB[i] = Be + (size_t)(n0 + r) * NH + srcoff;
  }
  int wst = w * 4096;                   // wave's 32-row LDS chunk (bytes)

  // ---- ds_read address components ----
  int swz0 = ((0 * 4 + g) ^ (cx & 7)) << 4;   // k-step 0: logical slots 0..3
  int swz1 = ((1 * 4 + g) ^ (cx & 7)) << 4;   // k-step 1: logical slots 4..7
  int arow = (wr * 64 + cx) * 128;
  int brow = (wc * 64 + cx) * 128;

  f32x4 acc[4][4] = {};

  const int NT = NH / 64;               // 64 K-tiles

  for (int t = 0; t < NT; t++) {
    gload16(pA[0] + (size_t)t*64, lds + wst);
    gload16(pA[1] + (size_t)t*64, lds + wst + 1024);
    gload16(pA[2] + (size_t)t*64, lds + wst + 2048);
    gload16(pA[3] + (size_t)t*64, lds + wst + 3072);
    gload16(pB[0] + (size_t)t*64, lds + 16384 + wst);
    gload16(pB[1] + (size_t)t*64, lds + 16384 + wst + 1024);
    gload16(pB[2] + (size_t)t*64, lds + 16384 + wst + 2048);
    gload16(pB[3] + (size_t)t*64, lds + 16384 + wst + 3072);
    __syncthreads();                    // compiler drains vmcnt before barrier

    s16x8 a0_[4], b0_[4], a1_[4], b1_[4];
    #pragma unroll
    for (int mf = 0; mf < 4; mf++) a0_[mf] = DSR(arow + mf*2048 + swz0);
    #pragma unroll
    for (int nf = 0; nf < 4; nf++) b0_[nf] = DSR(16384 + brow + nf*2048 + swz0);
    #pragma unroll
    for (int mf = 0; mf < 4; mf++)
      #pragma unroll
      for (int nf = 0; nf < 4; nf++)
        acc[mf][nf] = __builtin_amdgcn_mfma_f32_16x16x32_bf16(a0_[mf], b0_[nf], acc[mf][nf], 0, 0, 0);
    #pragma unroll
    for (int mf = 0; mf < 4; mf++) a1_[mf] = DSR(arow + mf*2048 + swz1);
    #pragma unroll
    for (int nf = 0; nf < 4; nf++) b1_[nf] = DSR(16384 + brow + nf*2048 + swz1);
    #pragma unroll
    for (int mf = 0; mf < 4; mf++)
      #pragma unroll
      for (int nf = 0; nf < 4; nf++)
        acc[mf][nf] = __builtin_amdgcn_mfma_f32_16x16x32_bf16(a1_[mf], b1_[nf], acc[mf][nf], 0, 0, 0);
    __syncthreads();                    // readers done before next overwrite
  }

  // ---- epilogue ----
  #pragma unroll
  for (int nf = 0; nf < 4; nf++) {
    int n = n0 + wc * 64 + nf * 16 + cx;
    if (MODE == 0 || n < NC) {
      float bv = bias[(size_t)e * (MODE == 0 ? NH : NC) + n];
      #pragma unroll
      for (int mf = 0; mf < 4; mf++) {
        f32x4 vacc = acc[mf][nf];
        #pragma unroll
        for (int i = 0; i < 4; i++) {
          int mrow = wr * 64 + mf * 16 + g * 4 + i;
          int mseg = m0 + mrow;
          if (mseg < cnt) {
            float u = vacc[i] + bv;
            if constexpr (MODE == 0) {
              float th = tanhf(0.79788456080286535588f * (u + 0.044715f * u * u * u));
              float hv = 0.5f * u * (1.0f + th);
              H1out[(size_t)(seg + mseg) * NH + n] = __float2bfloat16(hv);
            } else {
              int tok = rowtok[mrow];
              out[(size_t)tok * NC + n] = u;
            }
          }
        }
      }
    }
  }
}

// ================= Fallback kernels (Round-1, proven, ws-light) ===============
__global__ __launch_bounds__(256) void gemm1_k(
    const float* __restrict__ x, const float* __restrict__ W1,
    const float* __restrict__ b1, const int* __restrict__ perm,
    const int* __restrict__ counts, const int* __restrict__ offs,
    __hip_bfloat16* __restrict__ H1)
{
  int e = blockIdx.z;
  int cnt = counts[e];
  int m0 = blockIdx.y << 7;
  if (m0 >= cnt) return;
  int seg = offs[e];
  int n0 = blockIdx.x << 7;
  const float* W1e = W1 + (size_t)e * NH * NH;

  __shared__ __align__(16) char As[128*32*2];
  __shared__ __align__(16) char Bs[128*32*2];
  __shared__ int rowtok[128];

  int t = threadIdx.x;
  if (t < 128) {
    int rr = m0 + t; if (rr >= cnt) rr = cnt - 1;
    rowtok[t] = perm[seg + rr];
  }
  __syncthreads();

  int ar0 = t >> 2, as_ = t & 3;
  int ar1 = ar0 + 64;
  const float* asrc0 = x + (size_t)rowtok[ar0] * NH + (as_ << 3);
  const float* asrc1 = x + (size_t)rowtok[ar1] * NH + (as_ << 3);
  int aw0 = swz_off(ar0, as_), aw1 = swz_off(ar1, as_);
  int bnc = t & 31, bkp = t >> 5;
  const float* bsrc0 = W1e + (size_t)(bkp << 1) * NH + n0 + (bnc << 2);
  const float* bsrc1 = bsrc0 + (size_t)16 * NH;

  f32x4 acc[4][4] = {};

  int lane = t & 63, wid = t >> 6;
  int wm = (wid >> 1) << 6, wn = (wid & 1) << 6;
  int g = lane >> 4, cx = lane & 15;
  int aoff[4], boff[4];
  #pragma unroll
  for (int f = 0; f < 4; f++) {
    aoff[f] = swz_off(wm + (f << 4) + cx, g);
    boff[f] = swz_off(wn + (f << 4) + cx, g);
  }

  for (int kt = 0; kt < NH; kt += 32) {
    {
      f32x4 v0 = *(const f32x4*)(asrc0 + kt);
      f32x4 v1 = *(const f32x4*)(asrc0 + kt + 4);
      u32x4 wv = { cvtpk(v0[0],v0[1]), cvtpk(v0[2],v0[3]), cvtpk(v1[0],v1[1]), cvtpk(v1[2],v1[3]) };
      *(u32x4*)(As + aw0) = wv;
      f32x4 u0 = *(const f32x4*)(asrc1 + kt);
      f32x4 u1 = *(const f32x4*)(asrc1 + kt + 4);
      u32x4 w2 = { cvtpk(u0[0],u0[1]), cvtpk(u0[2],u0[3]), cvtpk(u1[0],u1[1]), cvtpk(u1[2],u1[3]) };
      *(u32x4*)(As + aw1) = w2;
    }
    {
      const float* p0 = bsrc0 + (size_t)kt * NH;
      f32x4 rr0 = *(const f32x4*)p0;
      f32x4 rr1 = *(const f32x4*)(p0 + NH);
      int kp = bkp, sl = kp >> 2, sub = (kp & 3) << 2;
      #pragma unroll
      for (int j = 0; j < 4; j++) {
        int n = (bnc << 2) + j;
        *(unsigned*)(Bs + (n << 6) + (((sl ^ (n ^ (n >> 2))) & 3) << 4) + sub) = cvtpk(rr0[j], rr1[j]);
      }
      const float* p1 = bsrc1 + (size_t)kt * NH;
      f32x4 q0 = *(const f32x4*)p1;
      f32x4 q1 = *(const f32x4*)(p1 + NH);
      kp = bkp + 8; sl = kp >> 2; sub = (kp & 3) << 2;
      #pragma unroll
      for (int j = 0; j < 4; j++) {
        int n = (bnc << 2) + j;
        *(unsigned*)(Bs + (n << 6) + (((sl ^ (n ^ (n >> 2))) & 3) << 4) + sub) = cvtpk(q0[j], q1[j]);
      }
    }
    __syncthreads();
    s16x8 af[4], bfr[4];
    #pragma unroll
    for (int f = 0; f < 4; f++) {
      af[f]  = *(const s16x8*)(As + aoff[f]);
      bfr[f] = *(const s16x8*)(Bs + boff[f]);
    }
    #pragma unroll
    for (int mf = 0; mf < 4; mf++)
      #pragma unroll
      for (int nf = 0; nf < 4; nf++)
        acc[mf][nf] = __builtin_amdgcn_mfma_f32_16x16x32_bf16(af[mf], bfr[nf], acc[mf][nf], 0, 0, 0);
    __syncthreads();
  }

  const float* b1e = b1 + (size_t)e * NH;
  #pragma unroll
  for (int nf = 0; nf < 4; nf++) {
    int n = n0 + wn + (nf << 4) + cx;
    float bv = b1e[n];
    #pragma unroll
    for (int mf = 0; mf < 4; mf++) {
      #pragma unroll
      for (int i = 0; i < 4; i++) {
        int mseg = m0 + wm + (mf << 4) + (g << 2) + i;
        if (mseg < cnt) {
          float u = acc[mf][nf][i] + bv;
          float th = tanhf(0.79788456080286535588f * (u + 0.044715f * u * u * u));
          float hv = 0.5f * u * (1.0f + th);
          H1[(size_t)(seg + mseg) * NH + n] = __float2bfloat16(hv);
        }
      }
    }
  }
}

__global__ __launch_bounds__(256) void gemm2_k(
    const __hip_bfloat16* __restrict__ H1, const float* __restrict__ W2,
    const float* __restrict__ b2, const int* __restrict__ perm,
    const int* __restrict__ counts, const int* __restrict__ offs,
    float* __restrict__ out)
{
  int e = blockIdx.z;
  int cnt = counts[e];
  int m0 = blockIdx.y << 7;
  if (m0 >= cnt) return;
  int seg = offs[e];
  int n0 = blockIdx.x << 7;
  const float* W2e = W2 + (size_t)e * NH * NC;

  __shared__ __align__(16) char As[128*32*2];
  __shared__ __align__(16) char Bs[128*32*2];
  __shared__ int rowtok[128];

  int t = threadIdx.x;
  if (t < 128) {
    int rr = m0 + t; if (rr >= cnt) rr = cnt - 1;
    rowtok[t] = perm[seg + rr];
  }
  __syncthreads();

  int ar0 = t >> 2, as_ = t & 3;
  int ar1 = ar0 + 64;
  int rA0 = m0 + ar0; if (rA0 >= cnt) rA0 = cnt - 1;
  int rA1 = m0 + ar1; if (rA1 >= cnt) rA1 = cnt - 1;
  const __hip_bfloat16* asrc0 = H1 + (size_t)(seg + rA0) * NH + (as_ << 3);
  const __hip_bfloat16* asrc1 = H1 + (size_t)(seg + rA1) * NH + (as_ << 3);
  int aw0 = swz_off(ar0, as_), aw1 = swz_off(ar1, as_);

  int bnc = t & 31, bkp = t >> 5;
  int col = n0 + (bnc << 2);
  bool bvalid = col < NC;
  const float* bsrc0 = W2e + (size_t)(bkp << 1) * NC + col;
  const float* bsrc1 = bsrc0 + (size_t)16 * NC;

  f32x4 acc[4][4] = {};

  int lane = t & 63, wid = t >> 6;
  int wm = (wid >> 1) << 6, wn = (wid & 1) << 6;
  int g = lane >> 4, cx = lane & 15;
  int aoff[4], boff[4];
  #pragma unroll
  for (int f = 0; f < 4; f++) {
    aoff[f] = swz_off(wm + (f << 4) + cx, g);
    boff[f] = swz_off(wn + (f << 4) + cx, g);
  }

  for (int kt = 0; kt < NH; kt += 32) {
    {
      *(u32x4*)(As + aw0) = *(const u32x4*)(asrc0 + kt);
      *(u32x4*)(As + aw1) = *(const u32x4*)(asrc1 + kt);
    }
    {
      f32x4 rr0 = {}, rr1 = {}, q0 = {}, q1 = {};
      if (bvalid) {
        const float* p0 = bsrc0 + (size_t)kt * NC;
        rr0 = *(const f32x4*)p0; rr1 = *(const f32x4*)(p0 + NC);
        const float* p1 = bsrc1 + (size_t)kt * NC;
        q0 = *(const f32x4*)p1; q1 = *(const f32x4*)(p1 + NC);
      }
      int kp = bkp, sl = kp >> 2, sub = (kp & 3) << 2;
      #pragma unroll
      for (int j = 0; j < 4; j++) {
        int n = (bnc << 2) + j;
        *(unsigned*)(Bs + (n << 6) + (((sl ^ (n ^ (n >> 2))) & 3) << 4) + sub) = cvtpk(rr0[j], rr1[j]);
      }
      kp = bkp + 8; sl = kp >> 2; sub = (kp & 3) << 2;
      #pragma unroll
      for (int j = 0; j < 4; j++) {
        int n = (bnc << 2) + j;
        *(unsigned*)(Bs + (n << 6) + (((sl ^ (n ^ (n >> 2))) & 3) << 4) + sub) = cvtpk(q0[j], q1[j]);
      }
    }
    __syncthreads();
    s16x8 af[4], bfr[4];
    #pragma unroll
    for (int f = 0; f < 4; f++) {
      af[f]  = *(const s16x8*)(As + aoff[f]);
      bfr[f] = *(const s16x8*)(Bs + boff[f]);
    }
    #pragma unroll
    for (int mf = 0; mf < 4; mf++)
      #pragma unroll
      for (int nf = 0; nf < 4; nf++)
        acc[mf][nf] = __builtin_amdgcn_mfma_f32_16x16x32_bf16(af[mf], bfr[nf], acc[mf][nf], 0, 0, 0);
    __syncthreads();
  }

  const float* b2e = b2 + (size_t)e * NC;
  #pragma unroll
  for (int nf = 0; nf < 4; nf++) {
    int n = n0 + wn + (nf << 4) + cx;
    if (n < NC) {
      float bv = b2e[n];
      #pragma unroll
      for (int mf = 0; mf < 4; mf++) {
        #pragma unroll
        for (int i = 0; i < 4; i++) {
          int mseg = m0 + wm + (mf << 4) + (g << 2) + i;
          if (mseg < cnt) {
            int tok = rowtok[wm + (mf << 4) + (g << 2) + i];
            out[(size_t)tok * NC + n] = acc[mf][nf][i] + bv;
          }
        }
      }
    }
  }
}

extern "C" void kernel_launch(void* const* d_in, const int* in_sizes, int n_in,
                              void* d_out, int out_size, void* d_ws, size_t ws_size,
                              hipStream_t stream) {
  const float* x  = (const float*)d_in[0];
  const float* Wr = (const float*)d_in[1];
  const float* br = (const float*)d_in[2];
  const float* W1 = (const float*)d_in[3];
  const float* b1 = (const float*)d_in[4];
  const float* W2 = (const float*)d_in[5];
  const float* b2 = (const float*)d_in[6];
  float* out = (float*)d_out;

  char* ws = (char*)d_ws;
  const size_t SZ_XB  = (size_t)NB * NH * 2;
  const size_t SZ_H1  = (size_t)NB * NH * 2;
  const size_t SZ_W1T = (size_t)NE * NH * NH * 2;
  const size_t SZ_W2T = (size_t)NE * NCP * NH * 2;
  const size_t need = SZ_XB + SZ_H1 + SZ_W1T + SZ_W2T + (size_t)NB*4*2 + 4096;

  if (ws_size >= need) {
    size_t o = 0;
    __hip_bfloat16* xb  = (__hip_bfloat16*)(ws + o); o += SZ_XB;
    __hip_bfloat16* H1  = (__hip_bfloat16*)(ws + o); o += SZ_H1;
    __hip_bfloat16* W1t = (__hip_bfloat16*)(ws + o); o += SZ_W1T;
    __hip_bfloat16* W2t = (__hip_bfloat16*)(ws + o); o += SZ_W2T;
    int* idx  = (int*)(ws + o); o += (size_t)NB * 4;
    int* perm = (int*)(ws + o); o += (size_t)NB * 4;
    char* small = ws + o;
    int*   cursors  = (int*)(small);
    int*   counts   = (int*)(small + 16);
    int*   offs     = (int*)(small + 32);
    int*   cnt_part = (int*)(small + 64);
    float* sum_part = (float*)(small + 64 + 1024);

    hipMemsetAsync(small, 0, 64 + 2048, stream);
    prep_k<<<10752, 256, 0, stream>>>(x, Wr, br, out, idx, cnt_part, sum_part, xb,
                                      W1, W1t, W2, W2t);
    finalize_k<<<1, 64, 0, stream>>>(cnt_part, sum_part, counts, offs, out);
    scatter_k<<<NB / 256, 256, 0, stream>>>(idx, offs, cursors, perm);
    gemmsb_k<0><<<dim3(32, 64, 4), 256, 0, stream>>>(xb, W1t, b1, perm, counts, offs, H1, nullptr);
    gemmsb_k<1><<<dim3(8, 64, 4), 256, 0, stream>>>(H1, W2t, b2, perm, counts, offs, nullptr, out);
  } else {
    __hip_bfloat16* H1 = (__hip_bfloat16*)ws;
    size_t o = (size_t)NB * NH * 2;
    int* idx  = (int*)(ws + o); o += (size_t)NB * 4;
    int* perm = (int*)(ws + o); o += (size_t)NB * 4;
    char* small = ws + o;
    int*   cursors  = (int*)(small);
    int*   counts   = (int*)(small + 16);
    int*   offs     = (int*)(small + 32);
    int*   cnt_part = (int*)(small + 64);
    float* sum_part = (float*)(small + 64 + 1024);

    hipMemsetAsync(small, 0, 64 + 2048, stream);
    router_k<<<NB, 256, 0, stream>>>(x, Wr, br, out, idx, cnt_part, sum_part);
    finalize_k<<<1, 64, 0, stream>>>(cnt_part, sum_part, counts, offs, out);
    scatter_k<<<NB / 256, 256, 0, stream>>>(idx, offs, cursors, perm);
    gemm1_k<<<dim3(32, 64, 4), 256, 0, stream>>>(x, W1, b1, perm, counts, offs, H1);
    gemm2_k<<<dim3(8, 64, 4), 256, 0, stream>>>(H1, W2, b2, perm, counts, offs, out);
  }
}